// Round 6
// baseline (885.613 us; speedup 1.0000x reference)
//
#include <hip/hip_runtime.h>
#include <hip/hip_bf16.h>

#define N_NODES 100000
#define N_EDGES 3200000
#define D_IN 256
#define HID 256
#define NC 40
#define NB_NODES ((N_NODES + 255) / 256)   /* 391 node-blocks */
#define EB ((N_EDGES + 255) / 256)         /* 12500 edge-blocks */

typedef unsigned short u16;
typedef unsigned int u32;
typedef __attribute__((ext_vector_type(8))) short bf16x8;
typedef __attribute__((ext_vector_type(4))) float f32x4;
typedef __attribute__((ext_vector_type(2))) float f32x2;

static __device__ __forceinline__ float bf2f(u16 u) {
  union { unsigned int i; float f; } c; c.i = ((unsigned int)u) << 16; return c.f;
}
static __device__ __forceinline__ u16 f2bf(float f) {
  union { float f; unsigned int i; } c; c.f = f;
  unsigned int x = c.i;
  x += 0x7fffu + ((x >> 16) & 1u);   // round-to-nearest-even
  return (u16)(x >> 16);
}

// ---- degree (int histogram; self-loop folded in later) ----------------------
__global__ void k_init(int* __restrict__ deg) {
  int i = blockIdx.x * 256 + threadIdx.x;
  if (i < N_NODES) deg[i] = 0;
}
__global__ void k_count(const int* __restrict__ ei, int* __restrict__ deg) {
  int e = blockIdx.x * 256 + threadIdx.x;
  if (e >= N_EDGES) return;
  unsigned d = (unsigned)ei[N_EDGES + e];
  if (d < N_NODES) atomicAdd(&deg[d], 1);   // native int atomic
}
__global__ void k_dinv(const int* __restrict__ deg, float* __restrict__ dinv) {
  int i = blockIdx.x * 256 + threadIdx.x;
  if (i < N_NODES) dinv[i] = rsqrtf((float)deg[i] + 1.0f);  // +1 self-loop
}

// ---- CSR build (rp = exclusive scan of edge in-degree) ----------------------
__global__ __launch_bounds__(256) void k_scan1(const int* __restrict__ deg,
    int* __restrict__ rp, int* __restrict__ bsums) {
  __shared__ int s[256];
  int t = threadIdx.x, i = blockIdx.x * 256 + t;
  int v = (i < N_NODES) ? deg[i] : 0;
  s[t] = v;
  __syncthreads();
  for (int off = 1; off < 256; off <<= 1) {
    int add = (t >= off) ? s[t - off] : 0;
    __syncthreads();
    s[t] += add;
    __syncthreads();
  }
  if (i < N_NODES) rp[i] = s[t] - v;
  if (t == 255) bsums[blockIdx.x] = s[255];
}
__global__ __launch_bounds__(512) void k_scan2(const int* __restrict__ bsums,
                                               int* __restrict__ boffs) {
  __shared__ int s[512];
  int t = threadIdx.x;
  int v = (t < NB_NODES) ? bsums[t] : 0;
  s[t] = v;
  __syncthreads();
  for (int off = 1; off < 512; off <<= 1) {
    int add = (t >= off) ? s[t - off] : 0;
    __syncthreads();
    s[t] += add;
    __syncthreads();
  }
  boffs[t] = s[t] - v;
}
__global__ void k_scan3(int* __restrict__ rp, const int* __restrict__ boffs,
                        int* __restrict__ cursor) {
  int i = blockIdx.x * 256 + threadIdx.x;
  if (i < N_NODES) {
    int v = rp[i] + boffs[blockIdx.x];
    rp[i] = v;
    cursor[i] = v;
  }
  if (i == 0) rp[N_NODES] = N_EDGES;
}
// 4B records: src only (weights are folded into y'/z' scaling)
__global__ void k_scatter(const int* __restrict__ ei,
    int* __restrict__ cursor, int* __restrict__ ed) {
  int e = blockIdx.x * 256 + threadIdx.x;
  if (e >= N_EDGES) return;
  unsigned s = (unsigned)ei[e];
  unsigned d = (unsigned)ei[N_EDGES + e];
  if (s >= N_NODES || d >= N_NODES) return;
  int pos = atomicAdd(&cursor[d], 1);
  if ((unsigned)pos < N_EDGES) ed[pos] = (int)s;
}

// ---- W1 -> W1^T bf16 --------------------------------------------------------
__global__ void k_w1t(const float* __restrict__ W1, u16* __restrict__ w1t) {
  int n = blockIdx.x, k = threadIdx.x;         // 256 x 256
  w1t[n * 256 + k] = f2bf(W1[k * 256 + n]);
}

// ---- GEMM1 (MFMA bf16): y'[100000,256]fp8 = dinv .* (x @ W1), 128x128 tile --
__global__ __launch_bounds__(256) void k_gemm1(const float* __restrict__ x,
    const u16* __restrict__ w1t, const float* __restrict__ dinv,
    unsigned char* __restrict__ y) {
  __shared__ char smem[20480];
  short* sA = (short*)smem;                    // [128][40] bf16 (pad 8)
  short* sB = (short*)(smem + 10240);          // [128][40]
  float* sdinv = (float*)(smem + 18432);       // 128 floats (epilogue only)
  int tid = threadIdx.x;
  int wave = tid >> 6, lane = tid & 63;
  int lq = lane >> 4, lr = lane & 15;
  int wm = (wave >> 1) * 64, wn = (wave & 1) * 64;
  int row0 = blockIdx.x * 128;
  int col0 = blockIdx.y * 128;
  int sr = tid >> 1;                           // staging row 0..127
  int sh = (tid & 1) * 16;                     // k-half in elements
  int arow = row0 + sr;
  bool aval = arow < N_NODES;
  const float* axf = x + (size_t)arow * 256 + sh;
  const u16* bx = w1t + (size_t)(col0 + sr) * 256 + sh;
  f32x4 acc[4][4] = {};
  for (int k0 = 0; k0 < 256; k0 += 32) {
    float4 f0 = {}, f1 = {}, f2 = {}, f3 = {};
    if (aval) {
      f0 = *(const float4*)(axf + k0);
      f1 = *(const float4*)(axf + k0 + 4);
      f2 = *(const float4*)(axf + k0 + 8);
      f3 = *(const float4*)(axf + k0 + 12);
    }
    uint4 vb0 = *(const uint4*)(bx + k0);
    uint4 vb1 = *(const uint4*)(bx + k0 + 8);
    uint4 pa0, pa1;
    pa0.x = (u32)f2bf(f0.x) | ((u32)f2bf(f0.y) << 16);
    pa0.y = (u32)f2bf(f0.z) | ((u32)f2bf(f0.w) << 16);
    pa0.z = (u32)f2bf(f1.x) | ((u32)f2bf(f1.y) << 16);
    pa0.w = (u32)f2bf(f1.z) | ((u32)f2bf(f1.w) << 16);
    pa1.x = (u32)f2bf(f2.x) | ((u32)f2bf(f2.y) << 16);
    pa1.y = (u32)f2bf(f2.z) | ((u32)f2bf(f2.w) << 16);
    pa1.z = (u32)f2bf(f3.x) | ((u32)f2bf(f3.y) << 16);
    pa1.w = (u32)f2bf(f3.z) | ((u32)f2bf(f3.w) << 16);
    __syncthreads();
    *(uint4*)&sA[sr * 40 + sh] = pa0;
    *(uint4*)&sA[sr * 40 + sh + 8] = pa1;
    *(uint4*)&sB[sr * 40 + sh] = vb0;
    *(uint4*)&sB[sr * 40 + sh + 8] = vb1;
    __syncthreads();
    bf16x8 af[4], bfr[4];
#pragma unroll
    for (int mt = 0; mt < 4; ++mt)
      af[mt] = *(const bf16x8*)&sA[(wm + mt * 16 + lr) * 40 + lq * 8];
#pragma unroll
    for (int nt = 0; nt < 4; ++nt)
      bfr[nt] = *(const bf16x8*)&sB[(wn + nt * 16 + lr) * 40 + lq * 8];
#pragma unroll
    for (int mt = 0; mt < 4; ++mt)
#pragma unroll
      for (int nt = 0; nt < 4; ++nt)
        acc[mt][nt] = __builtin_amdgcn_mfma_f32_16x16x32_bf16(
            af[mt], bfr[nt], acc[mt][nt], 0, 0, 0);
  }
  // epilogue: scale rows by dinv, fp8, LDS transpose
  __syncthreads();                 // all waves done reading sA/sB
  if (tid < 128) {
    int rr = row0 + tid;
    sdinv[tid] = (rr < N_NODES) ? dinv[rr] : 0.f;
  }
  __syncthreads();                 // sdinv ready (fp8 area [0,18432) untouched)
#pragma unroll
  for (int mt = 0; mt < 4; ++mt)
#pragma unroll
    for (int nt = 0; nt < 4; ++nt) {
      int c = wn + nt * 16 + lr;
#pragma unroll
      for (int i = 0; i < 4; ++i) {
        int r = wm + mt * 16 + lq * 4 + i;
        float sv = sdinv[r] * acc[mt][nt][i];
        int pk = __builtin_amdgcn_cvt_pk_fp8_f32(sv, sv, 0, false);
        smem[r * 144 + c] = (char)(pk & 0xFF);
      }
    }
  __syncthreads();
  if (aval) {
    unsigned char* dst = y + (size_t)arow * 256 + col0 + (tid & 1) * 64;
    const char* srcp = smem + sr * 144 + (tid & 1) * 64;
#pragma unroll
    for (int j = 0; j < 4; ++j)
      ((uint4*)dst)[j] = *(const uint4*)(srcp + j * 16);
  }
}

// ---- SpMM1: h1 = relu(dinv[row]*(y'[row] + sum y'[src]) + b1), 4x edge ILP --
__global__ __launch_bounds__(256) void k_spmm1(const u32* __restrict__ y32,
    const int* __restrict__ ed, const int* __restrict__ rp,
    const float* __restrict__ dinv, const float* __restrict__ b1,
    u16* __restrict__ h1) {
  int lane = threadIdx.x & 63;
  int row = (blockIdx.x << 2) + (threadIdx.x >> 6);
  float di = dinv[row];
  u32 v = y32[(size_t)row * 64 + lane];
  f32x2 lo = __builtin_amdgcn_cvt_pk_f32_fp8(v, false);
  f32x2 hi = __builtin_amdgcn_cvt_pk_f32_fp8(v, true);
  float a0 = lo.x, a1 = lo.y, a2 = hi.x, a3 = hi.y;
  int e = rp[row], e1 = rp[row + 1];
  for (; e + 4 <= e1; e += 4) {
    int s0 = ed[e], s1 = ed[e + 1], s2 = ed[e + 2], s3 = ed[e + 3];
    u32 u0 = y32[(size_t)s0 * 64 + lane];
    u32 u1 = y32[(size_t)s1 * 64 + lane];
    u32 u2 = y32[(size_t)s2 * 64 + lane];
    u32 u3 = y32[(size_t)s3 * 64 + lane];
    f32x2 l0 = __builtin_amdgcn_cvt_pk_f32_fp8(u0, false);
    f32x2 h0 = __builtin_amdgcn_cvt_pk_f32_fp8(u0, true);
    f32x2 l1 = __builtin_amdgcn_cvt_pk_f32_fp8(u1, false);
    f32x2 h1v = __builtin_amdgcn_cvt_pk_f32_fp8(u1, true);
    f32x2 l2 = __builtin_amdgcn_cvt_pk_f32_fp8(u2, false);
    f32x2 h2 = __builtin_amdgcn_cvt_pk_f32_fp8(u2, true);
    f32x2 l3 = __builtin_amdgcn_cvt_pk_f32_fp8(u3, false);
    f32x2 h3 = __builtin_amdgcn_cvt_pk_f32_fp8(u3, true);
    a0 += (l0.x + l1.x) + (l2.x + l3.x);
    a1 += (l0.y + l1.y) + (l2.y + l3.y);
    a2 += (h0.x + h1v.x) + (h2.x + h3.x);
    a3 += (h0.y + h1v.y) + (h2.y + h3.y);
  }
  for (; e < e1; ++e) {
    u32 u = y32[(size_t)ed[e] * 64 + lane];
    f32x2 l = __builtin_amdgcn_cvt_pk_f32_fp8(u, false);
    f32x2 h = __builtin_amdgcn_cvt_pk_f32_fp8(u, true);
    a0 += l.x; a1 += l.y; a2 += h.x; a3 += h.y;
  }
  float4 bb = *(const float4*)(b1 + lane * 4);
  a0 = fmaxf(di * a0 + bb.x, 0.f);
  a1 = fmaxf(di * a1 + bb.y, 0.f);
  a2 = fmaxf(di * a2 + bb.z, 0.f);
  a3 = fmaxf(di * a3 + bb.w, 0.f);
  ushort4 o;
  o.x = f2bf(a0); o.y = f2bf(a1); o.z = f2bf(a2); o.w = f2bf(a3);
  *(ushort4*)(h1 + (size_t)row * HID + lane * 4) = o;
}

// ---- GEMM2: z'[100000,40]bf16 = dinv .* (h1 @ W2), W2 in LDS ----------------
__global__ __launch_bounds__(256) void k_gemm2(const u16* __restrict__ h1,
    const float* __restrict__ W2, const float* __restrict__ dinv,
    u16* __restrict__ zb) {
  __shared__ float W2s[HID * NC];   // 40 KB
  for (int j = threadIdx.x; j < HID * NC; j += 256) W2s[j] = W2[j];
  __syncthreads();
  int idx = blockIdx.x * 256 + threadIdx.x;
  int r = idx / 10, q = idx % 10;
  if (r >= N_NODES) return;
  const u16* hr = h1 + (size_t)r * HID;
  float ax = 0.f, ay = 0.f, az = 0.f, aw = 0.f;
  for (int k = 0; k < HID; k += 4) {
    ushort4 hv = *(const ushort4*)(hr + k);
    float h0 = bf2f(hv.x), h1v = bf2f(hv.y), h2 = bf2f(hv.z), h3 = bf2f(hv.w);
    float4 w0 = *(const float4*)&W2s[(k + 0) * NC + q * 4];
    float4 w1 = *(const float4*)&W2s[(k + 1) * NC + q * 4];
    float4 w2 = *(const float4*)&W2s[(k + 2) * NC + q * 4];
    float4 w3 = *(const float4*)&W2s[(k + 3) * NC + q * 4];
    ax += h0 * w0.x + h1v * w1.x + h2 * w2.x + h3 * w3.x;
    ay += h0 * w0.y + h1v * w1.y + h2 * w2.y + h3 * w3.y;
    az += h0 * w0.z + h1v * w1.z + h2 * w2.z + h3 * w3.z;
    aw += h0 * w0.w + h1v * w1.w + h2 * w2.w + h3 * w3.w;
  }
  float sc = dinv[r];
  ushort4 o;
  o.x = f2bf(sc * ax); o.y = f2bf(sc * ay);
  o.z = f2bf(sc * az); o.w = f2bf(sc * aw);
  *(ushort4*)(zb + (size_t)r * NC + q * 4) = o;
}

// ---- SpMM2 + bias + log_softmax fused (z' bf16), 4x edge ILP ----------------
__global__ __launch_bounds__(256) void k_spmm2(const u16* __restrict__ zb,
    const int* __restrict__ ed, const int* __restrict__ rp,
    const float* __restrict__ dinv, const float* __restrict__ b2,
    float* __restrict__ out) {
  int lane = threadIdx.x & 63;
  int row = (blockIdx.x << 2) + (threadIdx.x >> 6);
  int col = (lane < NC) ? lane : 0;
  float di = dinv[row];
  float acc = bf2f(zb[(size_t)row * NC + col]);
  int e = rp[row], e1 = rp[row + 1];
  for (; e + 4 <= e1; e += 4) {
    int s0 = ed[e], s1 = ed[e + 1], s2 = ed[e + 2], s3 = ed[e + 3];
    u16 z0 = zb[(size_t)s0 * NC + col];
    u16 z1 = zb[(size_t)s1 * NC + col];
    u16 z2 = zb[(size_t)s2 * NC + col];
    u16 z3 = zb[(size_t)s3 * NC + col];
    acc += (bf2f(z0) + bf2f(z1)) + (bf2f(z2) + bf2f(z3));
  }
  for (; e < e1; ++e)
    acc += bf2f(zb[(size_t)ed[e] * NC + col]);
  acc = di * acc + b2[col];
  float mv = (lane < NC) ? acc : -3.0e38f;
  for (int off = 32; off > 0; off >>= 1) mv = fmaxf(mv, __shfl_xor(mv, off));
  float ex = (lane < NC) ? expf(acc - mv) : 0.f;
  float sum = ex;
  for (int off = 32; off > 0; off >>= 1) sum += __shfl_xor(sum, off);
  float res = acc - mv - logf(sum);
  if (lane < NC) out[(size_t)row * NC + lane] = res;
}

extern "C" void kernel_launch(void* const* d_in, const int* in_sizes, int n_in,
                              void* d_out, int out_size, void* d_ws, size_t ws_size,
                              hipStream_t stream) {
  const float* x  = (const float*)d_in[0];
  const int*   ei = (const int*)d_in[1];
  const float* W1 = (const float*)d_in[2];
  const float* b1 = (const float*)d_in[3];
  const float* W2 = (const float*)d_in[4];
  const float* b2 = (const float*)d_in[5];
  float* out = (float*)d_out;

  char* ws = (char*)d_ws;
  size_t off = 0;
  auto alloc = [&](size_t bytes) {
    char* p = ws + off;
    off = (off + bytes + 255) & ~(size_t)255;
    return p;
  };
  int*   deg    = (int*)  alloc((size_t)N_NODES * 4);
  float* dinv   = (float*)alloc((size_t)N_NODES * 4);
  int*   rp     = (int*)  alloc((size_t)(N_NODES + 1) * 4);
  int*   cursor = (int*)  alloc((size_t)N_NODES * 4);
  int*   bsums  = (int*)  alloc((size_t)NB_NODES * 4);
  int*   boffs  = (int*)  alloc((size_t)512 * 4);
  int*   ed     = (int*)  alloc((size_t)N_EDGES * 4);           // 12.8 MB
  unsigned char* y = (unsigned char*)alloc((size_t)N_NODES * 256); // 25.6 MB fp8
  u16*   w1t    = (u16*)  alloc((size_t)256 * 256 * 2);
  u16*   h1     = (u16*)  alloc((size_t)N_NODES * HID * 2);     // 51.2 MB
  u16*   zb     = (u16*)  alloc((size_t)N_NODES * NC * 2);      // 8 MB

  k_init<<<NB_NODES, 256, 0, stream>>>(deg);
  k_count<<<EB, 256, 0, stream>>>(ei, deg);
  k_dinv<<<NB_NODES, 256, 0, stream>>>(deg, dinv);
  k_scan1<<<NB_NODES, 256, 0, stream>>>(deg, rp, bsums);
  k_scan2<<<1, 512, 0, stream>>>(bsums, boffs);
  k_scan3<<<NB_NODES, 256, 0, stream>>>(rp, boffs, cursor);
  k_scatter<<<EB, 256, 0, stream>>>(ei, cursor, ed);
  k_w1t<<<256, 256, 0, stream>>>(W1, w1t);
  k_gemm1<<<dim3((N_NODES + 127) / 128, 2), 256, 0, stream>>>(x, w1t, dinv, y);
  k_spmm1<<<N_NODES / 4, 256, 0, stream>>>((const u32*)y, ed, rp, dinv, b1, h1);
  k_gemm2<<<(N_NODES * 10 + 255) / 256, 256, 0, stream>>>(h1, W2, dinv, zb);
  k_spmm2<<<N_NODES / 4, 256, 0, stream>>>(zb, ed, rp, dinv, b2, out);
}

// Round 7
// 690.773 us; speedup vs baseline: 1.2821x; 1.2821x over previous
//
#include <hip/hip_runtime.h>
#include <hip/hip_bf16.h>

#define N_NODES 100000
#define N_EDGES 3200000
#define D_IN 256
#define HID 256
#define NC 40
#define NB_NODES ((N_NODES + 255) / 256)   /* 391 node-blocks = buckets */
#define EB ((N_EDGES + 255) / 256)         /* 12500 edge-blocks */
#define NBUCK NB_NODES                     /* 391 buckets of 256 dst nodes */
#define CHUNK 8192
#define BIN1_BLOCKS ((N_EDGES + CHUNK - 1) / CHUNK)  /* 391 */

typedef unsigned short u16;
typedef unsigned int u32;
typedef __attribute__((ext_vector_type(8))) short bf16x8;
typedef __attribute__((ext_vector_type(4))) float f32x4;
typedef __attribute__((ext_vector_type(2))) float f32x2;

static __device__ __forceinline__ float bf2f(u16 u) {
  union { unsigned int i; float f; } c; c.i = ((unsigned int)u) << 16; return c.f;
}
static __device__ __forceinline__ u16 f2bf(float f) {
  union { float f; unsigned int i; } c; c.f = f;
  unsigned int x = c.i;
  x += 0x7fffu + ((x >> 16) & 1u);   // round-to-nearest-even
  return (u16)(x >> 16);
}

// ---- degree (int histogram; self-loop folded in later) ----------------------
__global__ void k_init(int* __restrict__ deg) {
  int i = blockIdx.x * 256 + threadIdx.x;
  if (i < N_NODES) deg[i] = 0;
}
__global__ void k_count(const int* __restrict__ ei, int* __restrict__ deg) {
  int e = blockIdx.x * 256 + threadIdx.x;
  if (e >= N_EDGES) return;
  unsigned d = (unsigned)ei[N_EDGES + e];
  if (d < N_NODES) atomicAdd(&deg[d], 1);   // native int atomic
}
__global__ void k_dinv(const int* __restrict__ deg, float* __restrict__ dinv) {
  int i = blockIdx.x * 256 + threadIdx.x;
  if (i < N_NODES) dinv[i] = rsqrtf((float)deg[i] + 1.0f);  // +1 self-loop
}

// ---- CSR row pointers (rp = exclusive scan of edge in-degree) ---------------
__global__ __launch_bounds__(256) void k_scan1(const int* __restrict__ deg,
    int* __restrict__ rp, int* __restrict__ bsums) {
  __shared__ int s[256];
  int t = threadIdx.x, i = blockIdx.x * 256 + t;
  int v = (i < N_NODES) ? deg[i] : 0;
  s[t] = v;
  __syncthreads();
  for (int off = 1; off < 256; off <<= 1) {
    int add = (t >= off) ? s[t - off] : 0;
    __syncthreads();
    s[t] += add;
    __syncthreads();
  }
  if (i < N_NODES) rp[i] = s[t] - v;
  if (t == 255) bsums[blockIdx.x] = s[255];
}
__global__ __launch_bounds__(512) void k_scan2(const int* __restrict__ bsums,
                                               int* __restrict__ boffs) {
  __shared__ int s[512];
  int t = threadIdx.x;
  int v = (t < NB_NODES) ? bsums[t] : 0;
  s[t] = v;
  __syncthreads();
  for (int off = 1; off < 512; off <<= 1) {
    int add = (t >= off) ? s[t - off] : 0;
    __syncthreads();
    s[t] += add;
    __syncthreads();
  }
  boffs[t] = s[t] - v;
}
__global__ void k_scan3(int* __restrict__ rp, const int* __restrict__ boffs) {
  int i = blockIdx.x * 256 + threadIdx.x;
  if (i < N_NODES) rp[i] += boffs[blockIdx.x];
  if (i == 0) rp[N_NODES] = N_EDGES;
}
// per-bucket cursor = CSR base of the bucket's dst range
__global__ void k_initcur(const int* __restrict__ rp, int* __restrict__ gcur) {
  int b = blockIdx.x * 256 + threadIdx.x;
  if (b < NBUCK) {
    int n = b * 256; if (n > N_NODES) n = N_NODES;
    gcur[b] = rp[n];
  }
}

// ---- binned CSR build, pass 1: group edges by 256-node dst bucket -----------
// binned record: (dst_local<<17) | src   (src < 2^17, dst_local < 256)
__global__ __launch_bounds__(256) void k_bin1(const int* __restrict__ ei,
    int* __restrict__ gcur, u32* __restrict__ binned) {
  __shared__ int cnt[NBUCK];
  __shared__ int base[NBUCK];
  int t = threadIdx.x;
  int e0 = blockIdx.x * CHUNK;
  for (int j = t; j < NBUCK; j += 256) cnt[j] = 0;
  __syncthreads();
  // phase A: local histogram by bucket
  for (int j = 0; j < CHUNK / 256; ++j) {
    int e = e0 + j * 256 + t;
    if (e < N_EDGES) {
      unsigned d = (unsigned)ei[N_EDGES + e];
      if (d < N_NODES) atomicAdd(&cnt[d >> 8], 1);
    }
  }
  __syncthreads();
  // phase B: reserve contiguous ranges
  for (int j = t; j < NBUCK; j += 256)
    base[j] = cnt[j] ? atomicAdd(&gcur[j], cnt[j]) : 0;
  __syncthreads();
  // phase C: write packed records grouped by bucket
  for (int j = 0; j < CHUNK / 256; ++j) {
    int e = e0 + j * 256 + t;
    if (e < N_EDGES) {
      unsigned s = (unsigned)ei[e];
      unsigned d = (unsigned)ei[N_EDGES + e];
      if (s < N_NODES && d < N_NODES) {
        int b = d >> 8;
        int pos = atomicAdd(&base[b], 1);
        if ((unsigned)pos < N_EDGES)
          binned[pos] = ((d & 255u) << 17) | s;
      }
    }
  }
}

// ---- pass 2: exact CSR within each bucket (stores stay in a ~32 KB window) --
__global__ __launch_bounds__(256) void k_bin2(const u32* __restrict__ binned,
    const int* __restrict__ rp, int* __restrict__ ed) {
  __shared__ int cursor[256];
  int b = blockIdx.x, t = threadIdx.x;
  int n = b * 256 + t;
  cursor[t] = rp[n < N_NODES ? n : N_NODES];
  int lo = b * 256; if (lo > N_NODES) lo = N_NODES;
  int hi = b * 256 + 256; if (hi > N_NODES) hi = N_NODES;
  int start = rp[lo], end = rp[hi];
  __syncthreads();
  for (int i = start + t; i < end; i += 256) {
    u32 v = binned[i];
    int dl = v >> 17;
    int pos = atomicAdd(&cursor[dl], 1);
    if ((unsigned)pos < N_EDGES) ed[pos] = (int)(v & 0x1FFFFu);
  }
}

// ---- W1 -> W1^T bf16 --------------------------------------------------------
__global__ void k_w1t(const float* __restrict__ W1, u16* __restrict__ w1t) {
  int n = blockIdx.x, k = threadIdx.x;         // 256 x 256
  w1t[n * 256 + k] = f2bf(W1[k * 256 + n]);
}

// ---- GEMM1 (MFMA bf16): y'[100000,256]fp8 = dinv .* (x @ W1), 128x128 tile --
__global__ __launch_bounds__(256) void k_gemm1(const float* __restrict__ x,
    const u16* __restrict__ w1t, const float* __restrict__ dinv,
    unsigned char* __restrict__ y) {
  __shared__ char smem[20480];
  short* sA = (short*)smem;                    // [128][40] bf16 (pad 8)
  short* sB = (short*)(smem + 10240);          // [128][40]
  float* sdinv = (float*)(smem + 18432);       // 128 floats (epilogue only)
  int tid = threadIdx.x;
  int wave = tid >> 6, lane = tid & 63;
  int lq = lane >> 4, lr = lane & 15;
  int wm = (wave >> 1) * 64, wn = (wave & 1) * 64;
  int row0 = blockIdx.x * 128;
  int col0 = blockIdx.y * 128;
  int sr = tid >> 1;                           // staging row 0..127
  int sh = (tid & 1) * 16;                     // k-half in elements
  int arow = row0 + sr;
  bool aval = arow < N_NODES;
  const float* axf = x + (size_t)arow * 256 + sh;
  const u16* bx = w1t + (size_t)(col0 + sr) * 256 + sh;
  f32x4 acc[4][4] = {};
  for (int k0 = 0; k0 < 256; k0 += 32) {
    float4 f0 = {}, f1 = {}, f2 = {}, f3 = {};
    if (aval) {
      f0 = *(const float4*)(axf + k0);
      f1 = *(const float4*)(axf + k0 + 4);
      f2 = *(const float4*)(axf + k0 + 8);
      f3 = *(const float4*)(axf + k0 + 12);
    }
    uint4 vb0 = *(const uint4*)(bx + k0);
    uint4 vb1 = *(const uint4*)(bx + k0 + 8);
    uint4 pa0, pa1;
    pa0.x = (u32)f2bf(f0.x) | ((u32)f2bf(f0.y) << 16);
    pa0.y = (u32)f2bf(f0.z) | ((u32)f2bf(f0.w) << 16);
    pa0.z = (u32)f2bf(f1.x) | ((u32)f2bf(f1.y) << 16);
    pa0.w = (u32)f2bf(f1.z) | ((u32)f2bf(f1.w) << 16);
    pa1.x = (u32)f2bf(f2.x) | ((u32)f2bf(f2.y) << 16);
    pa1.y = (u32)f2bf(f2.z) | ((u32)f2bf(f2.w) << 16);
    pa1.z = (u32)f2bf(f3.x) | ((u32)f2bf(f3.y) << 16);
    pa1.w = (u32)f2bf(f3.z) | ((u32)f2bf(f3.w) << 16);
    __syncthreads();
    *(uint4*)&sA[sr * 40 + sh] = pa0;
    *(uint4*)&sA[sr * 40 + sh + 8] = pa1;
    *(uint4*)&sB[sr * 40 + sh] = vb0;
    *(uint4*)&sB[sr * 40 + sh + 8] = vb1;
    __syncthreads();
    bf16x8 af[4], bfr[4];
#pragma unroll
    for (int mt = 0; mt < 4; ++mt)
      af[mt] = *(const bf16x8*)&sA[(wm + mt * 16 + lr) * 40 + lq * 8];
#pragma unroll
    for (int nt = 0; nt < 4; ++nt)
      bfr[nt] = *(const bf16x8*)&sB[(wn + nt * 16 + lr) * 40 + lq * 8];
#pragma unroll
    for (int mt = 0; mt < 4; ++mt)
#pragma unroll
      for (int nt = 0; nt < 4; ++nt)
        acc[mt][nt] = __builtin_amdgcn_mfma_f32_16x16x32_bf16(
            af[mt], bfr[nt], acc[mt][nt], 0, 0, 0);
  }
  // epilogue: scale rows by dinv, fp8, LDS transpose
  __syncthreads();
  if (tid < 128) {
    int rr = row0 + tid;
    sdinv[tid] = (rr < N_NODES) ? dinv[rr] : 0.f;
  }
  __syncthreads();
#pragma unroll
  for (int mt = 0; mt < 4; ++mt)
#pragma unroll
    for (int nt = 0; nt < 4; ++nt) {
      int c = wn + nt * 16 + lr;
#pragma unroll
      for (int i = 0; i < 4; ++i) {
        int r = wm + mt * 16 + lq * 4 + i;
        float sv = sdinv[r] * acc[mt][nt][i];
        int pk = __builtin_amdgcn_cvt_pk_fp8_f32(sv, sv, 0, false);
        smem[r * 144 + c] = (char)(pk & 0xFF);
      }
    }
  __syncthreads();
  if (aval) {
    unsigned char* dst = y + (size_t)arow * 256 + col0 + (tid & 1) * 64;
    const char* srcp = smem + sr * 144 + (tid & 1) * 64;
#pragma unroll
    for (int j = 0; j < 4; ++j)
      ((uint4*)dst)[j] = *(const uint4*)(srcp + j * 16);
  }
}

// ---- SpMM1: h1 = relu(dinv[row]*(y'[row] + sum y'[src]) + b1), 4x edge ILP --
__global__ __launch_bounds__(256) void k_spmm1(const u32* __restrict__ y32,
    const int* __restrict__ ed, const int* __restrict__ rp,
    const float* __restrict__ dinv, const float* __restrict__ b1,
    u16* __restrict__ h1) {
  int lane = threadIdx.x & 63;
  int row = (blockIdx.x << 2) + (threadIdx.x >> 6);
  float di = dinv[row];
  u32 v = y32[(size_t)row * 64 + lane];
  f32x2 lo = __builtin_amdgcn_cvt_pk_f32_fp8(v, false);
  f32x2 hi = __builtin_amdgcn_cvt_pk_f32_fp8(v, true);
  float a0 = lo.x, a1 = lo.y, a2 = hi.x, a3 = hi.y;
  int e = rp[row], e1 = rp[row + 1];
  for (; e + 4 <= e1; e += 4) {
    int s0 = ed[e], s1 = ed[e + 1], s2 = ed[e + 2], s3 = ed[e + 3];
    u32 u0 = y32[(size_t)s0 * 64 + lane];
    u32 u1 = y32[(size_t)s1 * 64 + lane];
    u32 u2 = y32[(size_t)s2 * 64 + lane];
    u32 u3 = y32[(size_t)s3 * 64 + lane];
    f32x2 l0 = __builtin_amdgcn_cvt_pk_f32_fp8(u0, false);
    f32x2 h0 = __builtin_amdgcn_cvt_pk_f32_fp8(u0, true);
    f32x2 l1 = __builtin_amdgcn_cvt_pk_f32_fp8(u1, false);
    f32x2 h1v = __builtin_amdgcn_cvt_pk_f32_fp8(u1, true);
    f32x2 l2 = __builtin_amdgcn_cvt_pk_f32_fp8(u2, false);
    f32x2 h2 = __builtin_amdgcn_cvt_pk_f32_fp8(u2, true);
    f32x2 l3 = __builtin_amdgcn_cvt_pk_f32_fp8(u3, false);
    f32x2 h3 = __builtin_amdgcn_cvt_pk_f32_fp8(u3, true);
    a0 += (l0.x + l1.x) + (l2.x + l3.x);
    a1 += (l0.y + l1.y) + (l2.y + l3.y);
    a2 += (h0.x + h1v.x) + (h2.x + h3.x);
    a3 += (h0.y + h1v.y) + (h2.y + h3.y);
  }
  for (; e < e1; ++e) {
    u32 u = y32[(size_t)ed[e] * 64 + lane];
    f32x2 l = __builtin_amdgcn_cvt_pk_f32_fp8(u, false);
    f32x2 h = __builtin_amdgcn_cvt_pk_f32_fp8(u, true);
    a0 += l.x; a1 += l.y; a2 += h.x; a3 += h.y;
  }
  float4 bb = *(const float4*)(b1 + lane * 4);
  a0 = fmaxf(di * a0 + bb.x, 0.f);
  a1 = fmaxf(di * a1 + bb.y, 0.f);
  a2 = fmaxf(di * a2 + bb.z, 0.f);
  a3 = fmaxf(di * a3 + bb.w, 0.f);
  ushort4 o;
  o.x = f2bf(a0); o.y = f2bf(a1); o.z = f2bf(a2); o.w = f2bf(a3);
  *(ushort4*)(h1 + (size_t)row * HID + lane * 4) = o;
}

// ---- GEMM2: z'[100000,40]bf16 = dinv .* (h1 @ W2), W2 in LDS ----------------
__global__ __launch_bounds__(256) void k_gemm2(const u16* __restrict__ h1,
    const float* __restrict__ W2, const float* __restrict__ dinv,
    u16* __restrict__ zb) {
  __shared__ float W2s[HID * NC];   // 40 KB
  for (int j = threadIdx.x; j < HID * NC; j += 256) W2s[j] = W2[j];
  __syncthreads();
  int idx = blockIdx.x * 256 + threadIdx.x;
  int r = idx / 10, q = idx % 10;
  if (r >= N_NODES) return;
  const u16* hr = h1 + (size_t)r * HID;
  float ax = 0.f, ay = 0.f, az = 0.f, aw = 0.f;
  for (int k = 0; k < HID; k += 4) {
    ushort4 hv = *(const ushort4*)(hr + k);
    float h0 = bf2f(hv.x), h1v = bf2f(hv.y), h2 = bf2f(hv.z), h3 = bf2f(hv.w);
    float4 w0 = *(const float4*)&W2s[(k + 0) * NC + q * 4];
    float4 w1 = *(const float4*)&W2s[(k + 1) * NC + q * 4];
    float4 w2 = *(const float4*)&W2s[(k + 2) * NC + q * 4];
    float4 w3 = *(const float4*)&W2s[(k + 3) * NC + q * 4];
    ax += h0 * w0.x + h1v * w1.x + h2 * w2.x + h3 * w3.x;
    ay += h0 * w0.y + h1v * w1.y + h2 * w2.y + h3 * w3.y;
    az += h0 * w0.z + h1v * w1.z + h2 * w2.z + h3 * w3.z;
    aw += h0 * w0.w + h1v * w1.w + h2 * w2.w + h3 * w3.w;
  }
  float sc = dinv[r];
  ushort4 o;
  o.x = f2bf(sc * ax); o.y = f2bf(sc * ay);
  o.z = f2bf(sc * az); o.w = f2bf(sc * aw);
  *(ushort4*)(zb + (size_t)r * NC + q * 4) = o;
}

// ---- SpMM2 + bias + log_softmax fused (z' bf16), 4x edge ILP ----------------
__global__ __launch_bounds__(256) void k_spmm2(const u16* __restrict__ zb,
    const int* __restrict__ ed, const int* __restrict__ rp,
    const float* __restrict__ dinv, const float* __restrict__ b2,
    float* __restrict__ out) {
  int lane = threadIdx.x & 63;
  int row = (blockIdx.x << 2) + (threadIdx.x >> 6);
  int col = (lane < NC) ? lane : 0;
  float di = dinv[row];
  float acc = bf2f(zb[(size_t)row * NC + col]);
  int e = rp[row], e1 = rp[row + 1];
  for (; e + 4 <= e1; e += 4) {
    int s0 = ed[e], s1 = ed[e + 1], s2 = ed[e + 2], s3 = ed[e + 3];
    u16 z0 = zb[(size_t)s0 * NC + col];
    u16 z1 = zb[(size_t)s1 * NC + col];
    u16 z2 = zb[(size_t)s2 * NC + col];
    u16 z3 = zb[(size_t)s3 * NC + col];
    acc += (bf2f(z0) + bf2f(z1)) + (bf2f(z2) + bf2f(z3));
  }
  for (; e < e1; ++e)
    acc += bf2f(zb[(size_t)ed[e] * NC + col]);
  acc = di * acc + b2[col];
  float mv = (lane < NC) ? acc : -3.0e38f;
  for (int off = 32; off > 0; off >>= 1) mv = fmaxf(mv, __shfl_xor(mv, off));
  float ex = (lane < NC) ? expf(acc - mv) : 0.f;
  float sum = ex;
  for (int off = 32; off > 0; off >>= 1) sum += __shfl_xor(sum, off);
  float res = acc - mv - logf(sum);
  if (lane < NC) out[(size_t)row * NC + lane] = res;
}

extern "C" void kernel_launch(void* const* d_in, const int* in_sizes, int n_in,
                              void* d_out, int out_size, void* d_ws, size_t ws_size,
                              hipStream_t stream) {
  const float* x  = (const float*)d_in[0];
  const int*   ei = (const int*)d_in[1];
  const float* W1 = (const float*)d_in[2];
  const float* b1 = (const float*)d_in[3];
  const float* W2 = (const float*)d_in[4];
  const float* b2 = (const float*)d_in[5];
  float* out = (float*)d_out;

  char* ws = (char*)d_ws;
  size_t off = 0;
  auto alloc = [&](size_t bytes) {
    char* p = ws + off;
    off = (off + bytes + 255) & ~(size_t)255;
    return p;
  };
  int*   deg    = (int*)  alloc((size_t)N_NODES * 4);
  float* dinv   = (float*)alloc((size_t)N_NODES * 4);
  int*   rp     = (int*)  alloc((size_t)(N_NODES + 1) * 4);
  int*   gcur   = (int*)  alloc((size_t)NBUCK * 4);
  int*   bsums  = (int*)  alloc((size_t)NB_NODES * 4);
  int*   boffs  = (int*)  alloc((size_t)512 * 4);
  u32*   binned = (u32*)  alloc((size_t)N_EDGES * 4);           // 12.8 MB
  int*   ed     = (int*)  alloc((size_t)N_EDGES * 4);           // 12.8 MB
  unsigned char* y = (unsigned char*)alloc((size_t)N_NODES * 256); // 25.6 MB fp8
  u16*   w1t    = (u16*)  alloc((size_t)256 * 256 * 2);
  u16*   h1     = (u16*)  alloc((size_t)N_NODES * HID * 2);     // 51.2 MB
  u16*   zb     = (u16*)  alloc((size_t)N_NODES * NC * 2);      // 8 MB

  k_init<<<NB_NODES, 256, 0, stream>>>(deg);
  k_count<<<EB, 256, 0, stream>>>(ei, deg);
  k_dinv<<<NB_NODES, 256, 0, stream>>>(deg, dinv);
  k_scan1<<<NB_NODES, 256, 0, stream>>>(deg, rp, bsums);
  k_scan2<<<1, 512, 0, stream>>>(bsums, boffs);
  k_scan3<<<NB_NODES, 256, 0, stream>>>(rp, boffs);
  k_initcur<<<(NBUCK + 255) / 256, 256, 0, stream>>>(rp, gcur);
  k_bin1<<<BIN1_BLOCKS, 256, 0, stream>>>(ei, gcur, binned);
  k_bin2<<<NBUCK, 256, 0, stream>>>(binned, rp, ed);
  k_w1t<<<256, 256, 0, stream>>>(W1, w1t);
  k_gemm1<<<dim3((N_NODES + 127) / 128, 2), 256, 0, stream>>>(x, w1t, dinv, y);
  k_spmm1<<<N_NODES / 4, 256, 0, stream>>>((const u32*)y, ed, rp, dinv, b1, h1);
  k_gemm2<<<(N_NODES * 10 + 255) / 256, 256, 0, stream>>>(h1, W2, dinv, zb);
  k_spmm2<<<N_NODES / 4, 256, 0, stream>>>(zb, ed, rp, dinv, b2, out);
}

// Round 8
// 587.887 us; speedup vs baseline: 1.5064x; 1.1750x over previous
//
#include <hip/hip_runtime.h>
#include <hip/hip_bf16.h>

#define N_NODES 100000
#define N_EDGES 3200000
#define D_IN 256
#define HID 256
#define NC 40
#define NBUCK 391                          /* buckets of 256 dst nodes */
#define CHUNK 8192
#define BIN1_BLOCKS ((N_EDGES + CHUNK - 1) / CHUNK)  /* 391 */

typedef unsigned short u16;
typedef unsigned int u32;
typedef __attribute__((ext_vector_type(8))) short bf16x8;
typedef __attribute__((ext_vector_type(4))) float f32x4;
typedef __attribute__((ext_vector_type(2))) float f32x2;

static __device__ __forceinline__ float bf2f(u16 u) {
  union { unsigned int i; float f; } c; c.i = ((unsigned int)u) << 16; return c.f;
}
static __device__ __forceinline__ u16 f2bf(float f) {
  union { float f; unsigned int i; } c; c.f = f;
  unsigned int x = c.i;
  x += 0x7fffu + ((x >> 16) & 1u);   // round-to-nearest-even
  return (u16)(x >> 16);
}

// ---- bucket totals: per-block LDS histogram, 1 global atomic/(block,bucket) -
__global__ void k_zero(int* __restrict__ gtot) {
  int i = blockIdx.x * 256 + threadIdx.x;
  if (i < NBUCK) gtot[i] = 0;
}
__global__ __launch_bounds__(256) void k_btot(const int* __restrict__ ei,
                                              int* __restrict__ gtot) {
  __shared__ int cnt[NBUCK];
  int t = threadIdx.x;
  int e0 = blockIdx.x * CHUNK;
  for (int j = t; j < NBUCK; j += 256) cnt[j] = 0;
  __syncthreads();
  for (int j = 0; j < CHUNK / 256; ++j) {
    int e = e0 + j * 256 + t;
    if (e < N_EDGES) {
      unsigned d = (unsigned)ei[N_EDGES + e];
      if (d < N_NODES) atomicAdd(&cnt[d >> 8], 1);
    }
  }
  __syncthreads();
  for (int j = t; j < NBUCK; j += 256)
    if (cnt[j]) atomicAdd(&gtot[j], cnt[j]);
}
// scan bucket totals -> bucket bases bb[0..NBUCK], init gcur
__global__ __launch_bounds__(512) void k_bscan(const int* __restrict__ gtot,
    int* __restrict__ bb, int* __restrict__ gcur) {
  __shared__ int s[512];
  int t = threadIdx.x;
  int v = (t < NBUCK) ? gtot[t] : 0;
  s[t] = v;
  __syncthreads();
  for (int off = 1; off < 512; off <<= 1) {
    int add = (t >= off) ? s[t - off] : 0;
    __syncthreads();
    s[t] += add;
    __syncthreads();
  }
  int excl = s[t] - v;
  if (t < NBUCK) { bb[t] = excl; gcur[t] = excl; }
  if (t == NBUCK - 1) bb[NBUCK] = excl + v;
}

// ---- binned CSR build, pass 1: group edges by 256-node dst bucket -----------
// record: (dst_local<<17) | src   (src < 2^17, dst_local < 256)
__global__ __launch_bounds__(256) void k_bin1(const int* __restrict__ ei,
    int* __restrict__ gcur, u32* __restrict__ binned) {
  __shared__ int cnt[NBUCK];
  __shared__ int base[NBUCK];
  int t = threadIdx.x;
  int e0 = blockIdx.x * CHUNK;
  for (int j = t; j < NBUCK; j += 256) cnt[j] = 0;
  __syncthreads();
  for (int j = 0; j < CHUNK / 256; ++j) {
    int e = e0 + j * 256 + t;
    if (e < N_EDGES) {
      unsigned d = (unsigned)ei[N_EDGES + e];
      if (d < N_NODES) atomicAdd(&cnt[d >> 8], 1);
    }
  }
  __syncthreads();
  for (int j = t; j < NBUCK; j += 256)
    base[j] = cnt[j] ? atomicAdd(&gcur[j], cnt[j]) : 0;
  __syncthreads();
  for (int j = 0; j < CHUNK / 256; ++j) {
    int e = e0 + j * 256 + t;
    if (e < N_EDGES) {
      unsigned s = (unsigned)ei[e];
      unsigned d = (unsigned)ei[N_EDGES + e];
      if (s < N_NODES && d < N_NODES) {
        int b = d >> 8;
        int pos = atomicAdd(&base[b], 1);
        if ((unsigned)pos < N_EDGES)
          binned[pos] = ((d & 255u) << 17) | s;
      }
    }
  }
}

// ---- pass 2: per-bucket node histogram + scan + scatter, all in LDS ---------
// writes rp, dinv, ed (deg = in-edge count; dinv = rsqrt(deg+1) self-loop)
__global__ __launch_bounds__(256) void k_bin2(const u32* __restrict__ binned,
    const int* __restrict__ bb, int* __restrict__ rp,
    float* __restrict__ dinv, int* __restrict__ ed) {
  __shared__ int cnt[256];
  __shared__ int s[256];
  __shared__ int cur[256];
  int b = blockIdx.x, t = threadIdx.x;
  int start = bb[b], end = bb[b + 1];
  cnt[t] = 0;
  __syncthreads();
  for (int i = start + t; i < end; i += 256)
    atomicAdd(&cnt[binned[i] >> 17], 1);
  __syncthreads();
  int v = cnt[t];
  s[t] = v;
  __syncthreads();
  for (int off = 1; off < 256; off <<= 1) {
    int add = (t >= off) ? s[t - off] : 0;
    __syncthreads();
    s[t] += add;
    __syncthreads();
  }
  int excl = s[t] - v;
  int n = b * 256 + t;
  if (n < N_NODES) {
    rp[n] = start + excl;
    dinv[n] = rsqrtf((float)v + 1.0f);
  }
  cur[t] = start + excl;
  if (b == NBUCK - 1 && t == 0) rp[N_NODES] = N_EDGES;
  __syncthreads();
  for (int i = start + t; i < end; i += 256) {
    u32 rec = binned[i];
    int pos = atomicAdd(&cur[rec >> 17], 1);
    if ((unsigned)pos < N_EDGES) ed[pos] = (int)(rec & 0x1FFFFu);
  }
}

// ---- W1 -> W1^T bf16 --------------------------------------------------------
__global__ void k_w1t(const float* __restrict__ W1, u16* __restrict__ w1t) {
  int n = blockIdx.x, k = threadIdx.x;         // 256 x 256
  w1t[n * 256 + k] = f2bf(W1[k * 256 + n]);
}

// ---- GEMM1 (MFMA bf16): y'[100000,256]fp8 = dinv .* (x @ W1), 128x128 tile --
__global__ __launch_bounds__(256) void k_gemm1(const float* __restrict__ x,
    const u16* __restrict__ w1t, const float* __restrict__ dinv,
    unsigned char* __restrict__ y) {
  __shared__ char smem[20480];
  short* sA = (short*)smem;                    // [128][40] bf16 (pad 8)
  short* sB = (short*)(smem + 10240);          // [128][40]
  float* sdinv = (float*)(smem + 18432);       // 128 floats (epilogue only)
  int tid = threadIdx.x;
  int wave = tid >> 6, lane = tid & 63;
  int lq = lane >> 4, lr = lane & 15;
  int wm = (wave >> 1) * 64, wn = (wave & 1) * 64;
  int row0 = blockIdx.x * 128;
  int col0 = blockIdx.y * 128;
  int sr = tid >> 1;                           // staging row 0..127
  int sh = (tid & 1) * 16;                     // k-half in elements
  int arow = row0 + sr;
  bool aval = arow < N_NODES;
  const float* axf = x + (size_t)arow * 256 + sh;
  const u16* bx = w1t + (size_t)(col0 + sr) * 256 + sh;
  f32x4 acc[4][4] = {};
  for (int k0 = 0; k0 < 256; k0 += 32) {
    float4 f0 = {}, f1 = {}, f2 = {}, f3 = {};
    if (aval) {
      f0 = *(const float4*)(axf + k0);
      f1 = *(const float4*)(axf + k0 + 4);
      f2 = *(const float4*)(axf + k0 + 8);
      f3 = *(const float4*)(axf + k0 + 12);
    }
    uint4 vb0 = *(const uint4*)(bx + k0);
    uint4 vb1 = *(const uint4*)(bx + k0 + 8);
    uint4 pa0, pa1;
    pa0.x = (u32)f2bf(f0.x) | ((u32)f2bf(f0.y) << 16);
    pa0.y = (u32)f2bf(f0.z) | ((u32)f2bf(f0.w) << 16);
    pa0.z = (u32)f2bf(f1.x) | ((u32)f2bf(f1.y) << 16);
    pa0.w = (u32)f2bf(f1.z) | ((u32)f2bf(f1.w) << 16);
    pa1.x = (u32)f2bf(f2.x) | ((u32)f2bf(f2.y) << 16);
    pa1.y = (u32)f2bf(f2.z) | ((u32)f2bf(f2.w) << 16);
    pa1.z = (u32)f2bf(f3.x) | ((u32)f2bf(f3.y) << 16);
    pa1.w = (u32)f2bf(f3.z) | ((u32)f2bf(f3.w) << 16);
    __syncthreads();
    *(uint4*)&sA[sr * 40 + sh] = pa0;
    *(uint4*)&sA[sr * 40 + sh + 8] = pa1;
    *(uint4*)&sB[sr * 40 + sh] = vb0;
    *(uint4*)&sB[sr * 40 + sh + 8] = vb1;
    __syncthreads();
    bf16x8 af[4], bfr[4];
#pragma unroll
    for (int mt = 0; mt < 4; ++mt)
      af[mt] = *(const bf16x8*)&sA[(wm + mt * 16 + lr) * 40 + lq * 8];
#pragma unroll
    for (int nt = 0; nt < 4; ++nt)
      bfr[nt] = *(const bf16x8*)&sB[(wn + nt * 16 + lr) * 40 + lq * 8];
#pragma unroll
    for (int mt = 0; mt < 4; ++mt)
#pragma unroll
      for (int nt = 0; nt < 4; ++nt)
        acc[mt][nt] = __builtin_amdgcn_mfma_f32_16x16x32_bf16(
            af[mt], bfr[nt], acc[mt][nt], 0, 0, 0);
  }
  __syncthreads();
  if (tid < 128) {
    int rr = row0 + tid;
    sdinv[tid] = (rr < N_NODES) ? dinv[rr] : 0.f;
  }
  __syncthreads();
#pragma unroll
  for (int mt = 0; mt < 4; ++mt)
#pragma unroll
    for (int nt = 0; nt < 4; ++nt) {
      int c = wn + nt * 16 + lr;
#pragma unroll
      for (int i = 0; i < 4; ++i) {
        int r = wm + mt * 16 + lq * 4 + i;
        float sv = sdinv[r] * acc[mt][nt][i];
        int pk = __builtin_amdgcn_cvt_pk_fp8_f32(sv, sv, 0, false);
        smem[r * 144 + c] = (char)(pk & 0xFF);
      }
    }
  __syncthreads();
  if (aval) {
    unsigned char* dst = y + (size_t)arow * 256 + col0 + (tid & 1) * 64;
    const char* srcp = smem + sr * 144 + (tid & 1) * 64;
#pragma unroll
    for (int j = 0; j < 4; ++j)
      ((uint4*)dst)[j] = *(const uint4*)(srcp + j * 16);
  }
}

// ---- SpMM1: h1 = relu(dinv[row]*(y'[row] + sum y'[src]) + b1), 4x edge ILP --
__global__ __launch_bounds__(256) void k_spmm1(const u32* __restrict__ y32,
    const int* __restrict__ ed, const int* __restrict__ rp,
    const float* __restrict__ dinv, const float* __restrict__ b1,
    u16* __restrict__ h1) {
  int lane = threadIdx.x & 63;
  int row = (blockIdx.x << 2) + (threadIdx.x >> 6);
  float di = dinv[row];
  u32 v = y32[(size_t)row * 64 + lane];
  f32x2 lo = __builtin_amdgcn_cvt_pk_f32_fp8(v, false);
  f32x2 hi = __builtin_amdgcn_cvt_pk_f32_fp8(v, true);
  float a0 = lo.x, a1 = lo.y, a2 = hi.x, a3 = hi.y;
  int e = rp[row], e1 = rp[row + 1];
  for (; e + 4 <= e1; e += 4) {
    int s0 = ed[e], s1 = ed[e + 1], s2 = ed[e + 2], s3 = ed[e + 3];
    u32 u0 = y32[(size_t)s0 * 64 + lane];
    u32 u1 = y32[(size_t)s1 * 64 + lane];
    u32 u2 = y32[(size_t)s2 * 64 + lane];
    u32 u3 = y32[(size_t)s3 * 64 + lane];
    f32x2 l0 = __builtin_amdgcn_cvt_pk_f32_fp8(u0, false);
    f32x2 h0 = __builtin_amdgcn_cvt_pk_f32_fp8(u0, true);
    f32x2 l1 = __builtin_amdgcn_cvt_pk_f32_fp8(u1, false);
    f32x2 h1v = __builtin_amdgcn_cvt_pk_f32_fp8(u1, true);
    f32x2 l2 = __builtin_amdgcn_cvt_pk_f32_fp8(u2, false);
    f32x2 h2 = __builtin_amdgcn_cvt_pk_f32_fp8(u2, true);
    f32x2 l3 = __builtin_amdgcn_cvt_pk_f32_fp8(u3, false);
    f32x2 h3 = __builtin_amdgcn_cvt_pk_f32_fp8(u3, true);
    a0 += (l0.x + l1.x) + (l2.x + l3.x);
    a1 += (l0.y + l1.y) + (l2.y + l3.y);
    a2 += (h0.x + h1v.x) + (h2.x + h3.x);
    a3 += (h0.y + h1v.y) + (h2.y + h3.y);
  }
  for (; e < e1; ++e) {
    u32 u = y32[(size_t)ed[e] * 64 + lane];
    f32x2 l = __builtin_amdgcn_cvt_pk_f32_fp8(u, false);
    f32x2 h = __builtin_amdgcn_cvt_pk_f32_fp8(u, true);
    a0 += l.x; a1 += l.y; a2 += h.x; a3 += h.y;
  }
  float4 bb = *(const float4*)(b1 + lane * 4);
  a0 = fmaxf(di * a0 + bb.x, 0.f);
  a1 = fmaxf(di * a1 + bb.y, 0.f);
  a2 = fmaxf(di * a2 + bb.z, 0.f);
  a3 = fmaxf(di * a3 + bb.w, 0.f);
  ushort4 o;
  o.x = f2bf(a0); o.y = f2bf(a1); o.z = f2bf(a2); o.w = f2bf(a3);
  *(ushort4*)(h1 + (size_t)row * HID + lane * 4) = o;
}

// ---- GEMM2: z'[100000,40]bf16 = dinv .* (h1 @ W2), W2 in LDS ----------------
__global__ __launch_bounds__(256) void k_gemm2(const u16* __restrict__ h1,
    const float* __restrict__ W2, const float* __restrict__ dinv,
    u16* __restrict__ zb) {
  __shared__ float W2s[HID * NC];   // 40 KB
  for (int j = threadIdx.x; j < HID * NC; j += 256) W2s[j] = W2[j];
  __syncthreads();
  int idx = blockIdx.x * 256 + threadIdx.x;
  int r = idx / 10, q = idx % 10;
  if (r >= N_NODES) return;
  const u16* hr = h1 + (size_t)r * HID;
  float ax = 0.f, ay = 0.f, az = 0.f, aw = 0.f;
  for (int k = 0; k < HID; k += 4) {
    ushort4 hv = *(const ushort4*)(hr + k);
    float h0 = bf2f(hv.x), h1v = bf2f(hv.y), h2 = bf2f(hv.z), h3 = bf2f(hv.w);
    float4 w0 = *(const float4*)&W2s[(k + 0) * NC + q * 4];
    float4 w1 = *(const float4*)&W2s[(k + 1) * NC + q * 4];
    float4 w2 = *(const float4*)&W2s[(k + 2) * NC + q * 4];
    float4 w3 = *(const float4*)&W2s[(k + 3) * NC + q * 4];
    ax += h0 * w0.x + h1v * w1.x + h2 * w2.x + h3 * w3.x;
    ay += h0 * w0.y + h1v * w1.y + h2 * w2.y + h3 * w3.y;
    az += h0 * w0.z + h1v * w1.z + h2 * w2.z + h3 * w3.z;
    aw += h0 * w0.w + h1v * w1.w + h2 * w2.w + h3 * w3.w;
  }
  float sc = dinv[r];
  ushort4 o;
  o.x = f2bf(sc * ax); o.y = f2bf(sc * ay);
  o.z = f2bf(sc * az); o.w = f2bf(sc * aw);
  *(ushort4*)(zb + (size_t)r * NC + q * 4) = o;
}

// ---- SpMM2 + bias + log_softmax fused (z' bf16), 4x edge ILP ----------------
__global__ __launch_bounds__(256) void k_spmm2(const u16* __restrict__ zb,
    const int* __restrict__ ed, const int* __restrict__ rp,
    const float* __restrict__ dinv, const float* __restrict__ b2,
    float* __restrict__ out) {
  int lane = threadIdx.x & 63;
  int row = (blockIdx.x << 2) + (threadIdx.x >> 6);
  int col = (lane < NC) ? lane : 0;
  float di = dinv[row];
  float acc = bf2f(zb[(size_t)row * NC + col]);
  int e = rp[row], e1 = rp[row + 1];
  for (; e + 4 <= e1; e += 4) {
    int s0 = ed[e], s1 = ed[e + 1], s2 = ed[e + 2], s3 = ed[e + 3];
    u16 z0 = zb[(size_t)s0 * NC + col];
    u16 z1 = zb[(size_t)s1 * NC + col];
    u16 z2 = zb[(size_t)s2 * NC + col];
    u16 z3 = zb[(size_t)s3 * NC + col];
    acc += (bf2f(z0) + bf2f(z1)) + (bf2f(z2) + bf2f(z3));
  }
  for (; e < e1; ++e)
    acc += bf2f(zb[(size_t)ed[e] * NC + col]);
  acc = di * acc + b2[col];
  float mv = (lane < NC) ? acc : -3.0e38f;
  for (int off = 32; off > 0; off >>= 1) mv = fmaxf(mv, __shfl_xor(mv, off));
  float ex = (lane < NC) ? expf(acc - mv) : 0.f;
  float sum = ex;
  for (int off = 32; off > 0; off >>= 1) sum += __shfl_xor(sum, off);
  float res = acc - mv - logf(sum);
  if (lane < NC) out[(size_t)row * NC + lane] = res;
}

extern "C" void kernel_launch(void* const* d_in, const int* in_sizes, int n_in,
                              void* d_out, int out_size, void* d_ws, size_t ws_size,
                              hipStream_t stream) {
  const float* x  = (const float*)d_in[0];
  const int*   ei = (const int*)d_in[1];
  const float* W1 = (const float*)d_in[2];
  const float* b1 = (const float*)d_in[3];
  const float* W2 = (const float*)d_in[4];
  const float* b2 = (const float*)d_in[5];
  float* out = (float*)d_out;

  char* ws = (char*)d_ws;
  size_t off = 0;
  auto alloc = [&](size_t bytes) {
    char* p = ws + off;
    off = (off + bytes + 255) & ~(size_t)255;
    return p;
  };
  int*   gtot   = (int*)  alloc((size_t)NBUCK * 4);
  int*   bb     = (int*)  alloc((size_t)(NBUCK + 1) * 4);
  int*   gcur   = (int*)  alloc((size_t)NBUCK * 4);
  int*   rp     = (int*)  alloc((size_t)(N_NODES + 1) * 4);
  float* dinv   = (float*)alloc((size_t)N_NODES * 4);
  u32*   binned = (u32*)  alloc((size_t)N_EDGES * 4);           // 12.8 MB
  int*   ed     = (int*)  alloc((size_t)N_EDGES * 4);           // 12.8 MB
  unsigned char* y = (unsigned char*)alloc((size_t)N_NODES * 256); // 25.6 MB fp8
  u16*   w1t    = (u16*)  alloc((size_t)256 * 256 * 2);
  u16*   h1     = (u16*)  alloc((size_t)N_NODES * HID * 2);     // 51.2 MB
  u16*   zb     = (u16*)  alloc((size_t)N_NODES * NC * 2);      // 8 MB

  k_zero<<<2, 256, 0, stream>>>(gtot);
  k_btot<<<BIN1_BLOCKS, 256, 0, stream>>>(ei, gtot);
  k_bscan<<<1, 512, 0, stream>>>(gtot, bb, gcur);
  k_bin1<<<BIN1_BLOCKS, 256, 0, stream>>>(ei, gcur, binned);
  k_bin2<<<NBUCK, 256, 0, stream>>>(binned, bb, rp, dinv, ed);
  k_w1t<<<256, 256, 0, stream>>>(W1, w1t);
  k_gemm1<<<dim3((N_NODES + 127) / 128, 2), 256, 0, stream>>>(x, w1t, dinv, y);
  k_spmm1<<<N_NODES / 4, 256, 0, stream>>>((const u32*)y, ed, rp, dinv, b1, h1);
  k_gemm2<<<(N_NODES * 10 + 255) / 256, 256, 0, stream>>>(h1, W2, dinv, zb);
  k_spmm2<<<N_NODES / 4, 256, 0, stream>>>(zb, ed, rp, dinv, b2, out);
}

// Round 9
// 520.577 us; speedup vs baseline: 1.7012x; 1.1293x over previous
//
#include <hip/hip_runtime.h>
#include <hip/hip_bf16.h>

#define N_NODES 100000
#define N_EDGES 3200000
#define D_IN 256
#define HID 256
#define NC 40
#define NBUCK 391                          /* buckets of 256 dst nodes */
#define CHUNK 8192
#define BIN1_BLOCKS ((N_EDGES + CHUNK - 1) / CHUNK)  /* 391 */
#define BCAP 16384                         /* padded slots per bucket */
#define NPADE (NBUCK * BCAP)               /* 6406144 padded edge slots */

typedef unsigned short u16;
typedef unsigned int u32;
typedef __attribute__((ext_vector_type(8))) short bf16x8;
typedef __attribute__((ext_vector_type(4))) float f32x4;
typedef __attribute__((ext_vector_type(2))) float f32x2;

static __device__ __forceinline__ float bf2f(u16 u) {
  union { unsigned int i; float f; } c; c.i = ((unsigned int)u) << 16; return c.f;
}
static __device__ __forceinline__ u16 f2bf(float f) {
  union { float f; unsigned int i; } c; c.f = f;
  unsigned int x = c.i;
  x += 0x7fffu + ((x >> 16) & 1u);   // round-to-nearest-even
  return (u16)(x >> 16);
}

// ---- init per-bucket cursors to padded bases --------------------------------
__global__ void k_zero(int* __restrict__ gcur) {
  int i = blockIdx.x * 256 + threadIdx.x;
  if (i < NBUCK) gcur[i] = i * BCAP;
}

// ---- binned CSR pass 1: group edges into padded 256-node dst buckets --------
// record: (dst_local<<17) | src   (src < 2^17, dst_local < 256)
__global__ __launch_bounds__(256) void k_bin1(const int* __restrict__ ei,
    int* __restrict__ gcur, u32* __restrict__ binned) {
  __shared__ int cnt[NBUCK];
  __shared__ int base[NBUCK];
  int t = threadIdx.x;
  int e0 = blockIdx.x * CHUNK;
  for (int j = t; j < NBUCK; j += 256) cnt[j] = 0;
  __syncthreads();
  for (int j = 0; j < CHUNK / 256; ++j) {
    int e = e0 + j * 256 + t;
    if (e < N_EDGES) {
      unsigned d = (unsigned)ei[N_EDGES + e];
      if (d < N_NODES) atomicAdd(&cnt[d >> 8], 1);
    }
  }
  __syncthreads();
  for (int j = t; j < NBUCK; j += 256)
    base[j] = cnt[j] ? atomicAdd(&gcur[j], cnt[j]) : 0;
  __syncthreads();
  for (int j = 0; j < CHUNK / 256; ++j) {
    int e = e0 + j * 256 + t;
    if (e < N_EDGES) {
      unsigned s = (unsigned)ei[e];
      unsigned d = (unsigned)ei[N_EDGES + e];
      if (s < N_NODES && d < N_NODES) {
        int b = d >> 8;
        int pos = atomicAdd(&base[b], 1);
        if ((unsigned)pos < NPADE)
          binned[pos] = ((d & 255u) << 17) | s;
      }
    }
  }
}

// ---- pass 2: per-bucket histogram + scan + scatter in LDS; emits rp/re/dinv -
__global__ __launch_bounds__(256) void k_bin2(const u32* __restrict__ binned,
    const int* __restrict__ gcur, int* __restrict__ rp, int* __restrict__ re,
    float* __restrict__ dinv, int* __restrict__ ed) {
  __shared__ int cnt[256];
  __shared__ int s[256];
  __shared__ int cur[256];
  int b = blockIdx.x, t = threadIdx.x;
  int start = b * BCAP, end = gcur[b];
  cnt[t] = 0;
  __syncthreads();
  for (int i = start + t; i < end; i += 256)
    atomicAdd(&cnt[binned[i] >> 17], 1);
  __syncthreads();
  int v = cnt[t];
  s[t] = v;
  __syncthreads();
  for (int off = 1; off < 256; off <<= 1) {
    int add = (t >= off) ? s[t - off] : 0;
    __syncthreads();
    s[t] += add;
    __syncthreads();
  }
  int excl = s[t] - v;
  int n = b * 256 + t;
  if (n < N_NODES) {
    rp[n] = start + excl;
    re[n] = start + excl + v;
    dinv[n] = rsqrtf((float)v + 1.0f);   // +1 self-loop
  }
  cur[t] = start + excl;
  __syncthreads();
  for (int i = start + t; i < end; i += 256) {
    u32 rec = binned[i];
    int pos = atomicAdd(&cur[rec >> 17], 1);
    if ((unsigned)pos < NPADE) ed[pos] = (int)(rec & 0x1FFFFu);
  }
}

// ---- weight transposes ------------------------------------------------------
__global__ void k_w1t(const float* __restrict__ W1, u16* __restrict__ w1t) {
  int n = blockIdx.x, k = threadIdx.x;         // 256 x 256
  w1t[n * 256 + k] = f2bf(W1[k * 256 + n]);
}
__global__ void k_w2t(const float* __restrict__ W2, u16* __restrict__ w2t) {
  int n = blockIdx.x, k = threadIdx.x;         // 48 x 256 (pad cols 40..47 = 0)
  w2t[n * 256 + k] = (n < NC) ? f2bf(W2[k * NC + n]) : (u16)0;
}

// ---- GEMM1 (MFMA bf16): y'[100000,256]fp8 = dinv .* (x @ W1), 128x128 tile --
__global__ __launch_bounds__(256) void k_gemm1(const float* __restrict__ x,
    const u16* __restrict__ w1t, const float* __restrict__ dinv,
    unsigned char* __restrict__ y) {
  __shared__ char smem[20480];
  short* sA = (short*)smem;                    // [128][40] bf16 (pad 8)
  short* sB = (short*)(smem + 10240);          // [128][40]
  float* sdinv = (float*)(smem + 18432);       // 128 floats (epilogue only)
  int tid = threadIdx.x;
  int wave = tid >> 6, lane = tid & 63;
  int lq = lane >> 4, lr = lane & 15;
  int wm = (wave >> 1) * 64, wn = (wave & 1) * 64;
  int row0 = blockIdx.x * 128;
  int col0 = blockIdx.y * 128;
  int sr = tid >> 1;                           // staging row 0..127
  int sh = (tid & 1) * 16;                     // k-half in elements
  int arow = row0 + sr;
  bool aval = arow < N_NODES;
  const float* axf = x + (size_t)arow * 256 + sh;
  const u16* bx = w1t + (size_t)(col0 + sr) * 256 + sh;
  f32x4 acc[4][4] = {};
  for (int k0 = 0; k0 < 256; k0 += 32) {
    float4 f0 = {}, f1 = {}, f2 = {}, f3 = {};
    if (aval) {
      f0 = *(const float4*)(axf + k0);
      f1 = *(const float4*)(axf + k0 + 4);
      f2 = *(const float4*)(axf + k0 + 8);
      f3 = *(const float4*)(axf + k0 + 12);
    }
    uint4 vb0 = *(const uint4*)(bx + k0);
    uint4 vb1 = *(const uint4*)(bx + k0 + 8);
    uint4 pa0, pa1;
    pa0.x = (u32)f2bf(f0.x) | ((u32)f2bf(f0.y) << 16);
    pa0.y = (u32)f2bf(f0.z) | ((u32)f2bf(f0.w) << 16);
    pa0.z = (u32)f2bf(f1.x) | ((u32)f2bf(f1.y) << 16);
    pa0.w = (u32)f2bf(f1.z) | ((u32)f2bf(f1.w) << 16);
    pa1.x = (u32)f2bf(f2.x) | ((u32)f2bf(f2.y) << 16);
    pa1.y = (u32)f2bf(f2.z) | ((u32)f2bf(f2.w) << 16);
    pa1.z = (u32)f2bf(f3.x) | ((u32)f2bf(f3.y) << 16);
    pa1.w = (u32)f2bf(f3.z) | ((u32)f2bf(f3.w) << 16);
    __syncthreads();
    *(uint4*)&sA[sr * 40 + sh] = pa0;
    *(uint4*)&sA[sr * 40 + sh + 8] = pa1;
    *(uint4*)&sB[sr * 40 + sh] = vb0;
    *(uint4*)&sB[sr * 40 + sh + 8] = vb1;
    __syncthreads();
    bf16x8 af[4], bfr[4];
#pragma unroll
    for (int mt = 0; mt < 4; ++mt)
      af[mt] = *(const bf16x8*)&sA[(wm + mt * 16 + lr) * 40 + lq * 8];
#pragma unroll
    for (int nt = 0; nt < 4; ++nt)
      bfr[nt] = *(const bf16x8*)&sB[(wn + nt * 16 + lr) * 40 + lq * 8];
#pragma unroll
    for (int mt = 0; mt < 4; ++mt)
#pragma unroll
      for (int nt = 0; nt < 4; ++nt)
        acc[mt][nt] = __builtin_amdgcn_mfma_f32_16x16x32_bf16(
            af[mt], bfr[nt], acc[mt][nt], 0, 0, 0);
  }
  __syncthreads();
  if (tid < 128) {
    int rr = row0 + tid;
    sdinv[tid] = (rr < N_NODES) ? dinv[rr] : 0.f;
  }
  __syncthreads();
#pragma unroll
  for (int mt = 0; mt < 4; ++mt)
#pragma unroll
    for (int nt = 0; nt < 4; ++nt) {
      int c = wn + nt * 16 + lr;
#pragma unroll
      for (int i = 0; i < 4; ++i) {
        int r = wm + mt * 16 + lq * 4 + i;
        float sv = sdinv[r] * acc[mt][nt][i];
        int pk = __builtin_amdgcn_cvt_pk_fp8_f32(sv, sv, 0, false);
        smem[r * 144 + c] = (char)(pk & 0xFF);
      }
    }
  __syncthreads();
  if (aval) {
    unsigned char* dst = y + (size_t)arow * 256 + col0 + (tid & 1) * 64;
    const char* srcp = smem + sr * 144 + (tid & 1) * 64;
#pragma unroll
    for (int j = 0; j < 4; ++j)
      ((uint4*)dst)[j] = *(const uint4*)(srcp + j * 16);
  }
}

// ---- SpMM1: h1 = relu(dinv*(y'[row]+sum y'[src])+b1), 8x edge ILP, pk adds --
__global__ __launch_bounds__(256) void k_spmm1(const u32* __restrict__ y32,
    const int* __restrict__ ed, const int* __restrict__ rp,
    const int* __restrict__ re, const float* __restrict__ dinv,
    const float* __restrict__ b1, u16* __restrict__ h1) {
  int lane = threadIdx.x & 63;
  int row = (blockIdx.x << 2) + (threadIdx.x >> 6);
  float di = dinv[row];
  u32 v = y32[(size_t)row * 64 + lane];
  f32x2 alo = __builtin_amdgcn_cvt_pk_f32_fp8(v, false);
  f32x2 ahi = __builtin_amdgcn_cvt_pk_f32_fp8(v, true);
  int e = rp[row], e1 = re[row];
  for (; e + 8 <= e1; e += 8) {
    int s0 = ed[e], s1 = ed[e + 1], s2 = ed[e + 2], s3 = ed[e + 3];
    int s4 = ed[e + 4], s5 = ed[e + 5], s6 = ed[e + 6], s7 = ed[e + 7];
    u32 u0 = y32[(size_t)s0 * 64 + lane];
    u32 u1 = y32[(size_t)s1 * 64 + lane];
    u32 u2 = y32[(size_t)s2 * 64 + lane];
    u32 u3 = y32[(size_t)s3 * 64 + lane];
    u32 u4 = y32[(size_t)s4 * 64 + lane];
    u32 u5 = y32[(size_t)s5 * 64 + lane];
    u32 u6 = y32[(size_t)s6 * 64 + lane];
    u32 u7 = y32[(size_t)s7 * 64 + lane];
    alo += __builtin_amdgcn_cvt_pk_f32_fp8(u0, false);
    ahi += __builtin_amdgcn_cvt_pk_f32_fp8(u0, true);
    alo += __builtin_amdgcn_cvt_pk_f32_fp8(u1, false);
    ahi += __builtin_amdgcn_cvt_pk_f32_fp8(u1, true);
    alo += __builtin_amdgcn_cvt_pk_f32_fp8(u2, false);
    ahi += __builtin_amdgcn_cvt_pk_f32_fp8(u2, true);
    alo += __builtin_amdgcn_cvt_pk_f32_fp8(u3, false);
    ahi += __builtin_amdgcn_cvt_pk_f32_fp8(u3, true);
    alo += __builtin_amdgcn_cvt_pk_f32_fp8(u4, false);
    ahi += __builtin_amdgcn_cvt_pk_f32_fp8(u4, true);
    alo += __builtin_amdgcn_cvt_pk_f32_fp8(u5, false);
    ahi += __builtin_amdgcn_cvt_pk_f32_fp8(u5, true);
    alo += __builtin_amdgcn_cvt_pk_f32_fp8(u6, false);
    ahi += __builtin_amdgcn_cvt_pk_f32_fp8(u6, true);
    alo += __builtin_amdgcn_cvt_pk_f32_fp8(u7, false);
    ahi += __builtin_amdgcn_cvt_pk_f32_fp8(u7, true);
  }
  for (; e + 2 <= e1; e += 2) {
    int s0 = ed[e], s1 = ed[e + 1];
    u32 u0 = y32[(size_t)s0 * 64 + lane];
    u32 u1 = y32[(size_t)s1 * 64 + lane];
    alo += __builtin_amdgcn_cvt_pk_f32_fp8(u0, false);
    ahi += __builtin_amdgcn_cvt_pk_f32_fp8(u0, true);
    alo += __builtin_amdgcn_cvt_pk_f32_fp8(u1, false);
    ahi += __builtin_amdgcn_cvt_pk_f32_fp8(u1, true);
  }
  if (e < e1) {
    u32 u = y32[(size_t)ed[e] * 64 + lane];
    alo += __builtin_amdgcn_cvt_pk_f32_fp8(u, false);
    ahi += __builtin_amdgcn_cvt_pk_f32_fp8(u, true);
  }
  float4 bb = *(const float4*)(b1 + lane * 4);
  float a0 = fmaxf(di * alo.x + bb.x, 0.f);
  float a1 = fmaxf(di * alo.y + bb.y, 0.f);
  float a2 = fmaxf(di * ahi.x + bb.z, 0.f);
  float a3 = fmaxf(di * ahi.y + bb.w, 0.f);
  ushort4 o;
  o.x = f2bf(a0); o.y = f2bf(a1); o.z = f2bf(a2); o.w = f2bf(a3);
  *(ushort4*)(h1 + (size_t)row * HID + lane * 4) = o;
}

// ---- GEMM2 (MFMA bf16): z'[100000,40]bf16 = dinv .* (h1 @ W2), 128x48 tile --
__global__ __launch_bounds__(256) void k_gemm2(const u16* __restrict__ h1,
    const u16* __restrict__ w2t, const float* __restrict__ dinv,
    u16* __restrict__ zb) {
  __shared__ char smem[16384];
  short* sA = (short*)smem;                    // [128][40] bf16
  short* sB = (short*)(smem + 10240);          // [48][40]
  float* sdinv = (float*)(smem + 14336);       // 128 floats
  u16* sC = (u16*)smem;                        // [128][56] epilogue overlay
  int tid = threadIdx.x;
  int wave = tid >> 6, lane = tid & 63;
  int lq = lane >> 4, lr = lane & 15;
  int wm = wave * 32;
  int row0 = blockIdx.x * 128;
  int sr = tid >> 1;
  int sh = (tid & 1) * 16;
  int arow = row0 + sr;
  bool aval = arow < N_NODES;
  const u16* ax = h1 + (size_t)arow * 256 + sh;
  int br = tid >> 1;                           // B staging row (t<96)
  const u16* bx = w2t + (size_t)br * 256 + sh;
  if (tid < 128) {
    int rr = row0 + tid;
    sdinv[tid] = (rr < N_NODES) ? dinv[rr] : 0.f;
  }
  f32x4 acc[2][3] = {};
  for (int k0 = 0; k0 < 256; k0 += 32) {
    uint4 a0 = {}, a1 = {};
    if (aval) {
      a0 = *(const uint4*)(ax + k0);
      a1 = *(const uint4*)(ax + k0 + 8);
    }
    uint4 b0 = {}, b1v = {};
    if (tid < 96) {
      b0 = *(const uint4*)(bx + k0);
      b1v = *(const uint4*)(bx + k0 + 8);
    }
    __syncthreads();
    *(uint4*)&sA[sr * 40 + sh] = a0;
    *(uint4*)&sA[sr * 40 + sh + 8] = a1;
    if (tid < 96) {
      *(uint4*)&sB[br * 40 + sh] = b0;
      *(uint4*)&sB[br * 40 + sh + 8] = b1v;
    }
    __syncthreads();
    bf16x8 af[2], bfr[3];
#pragma unroll
    for (int mt = 0; mt < 2; ++mt)
      af[mt] = *(const bf16x8*)&sA[(wm + mt * 16 + lr) * 40 + lq * 8];
#pragma unroll
    for (int nt = 0; nt < 3; ++nt)
      bfr[nt] = *(const bf16x8*)&sB[(nt * 16 + lr) * 40 + lq * 8];
#pragma unroll
    for (int mt = 0; mt < 2; ++mt)
#pragma unroll
      for (int nt = 0; nt < 3; ++nt)
        acc[mt][nt] = __builtin_amdgcn_mfma_f32_16x16x32_bf16(
            af[mt], bfr[nt], acc[mt][nt], 0, 0, 0);
  }
  __syncthreads();
#pragma unroll
  for (int mt = 0; mt < 2; ++mt)
#pragma unroll
    for (int nt = 0; nt < 3; ++nt) {
      int c = nt * 16 + lr;
#pragma unroll
      for (int i = 0; i < 4; ++i) {
        int r = wm + mt * 16 + lq * 4 + i;
        sC[r * 56 + c] = f2bf(sdinv[r] * acc[mt][nt][i]);
      }
    }
  __syncthreads();
  if (tid < 128) {
    int orow = row0 + tid;
    if (orow < N_NODES) {
      u16* dst = zb + (size_t)orow * NC;       // 80 B per row, 16B-aligned
#pragma unroll
      for (int j = 0; j < 5; ++j)
        ((uint4*)dst)[j] = *(const uint4*)&sC[tid * 56 + j * 8];
    }
  }
}

// ---- SpMM2 + bias + log_softmax fused (z' bf16), 8x edge ILP ----------------
__global__ __launch_bounds__(256) void k_spmm2(const u16* __restrict__ zb,
    const int* __restrict__ ed, const int* __restrict__ rp,
    const int* __restrict__ re, const float* __restrict__ dinv,
    const float* __restrict__ b2, float* __restrict__ out) {
  int lane = threadIdx.x & 63;
  int row = (blockIdx.x << 2) + (threadIdx.x >> 6);
  int col = (lane < NC) ? lane : 0;
  float di = dinv[row];
  float acc = bf2f(zb[(size_t)row * NC + col]);
  int e = rp[row], e1 = re[row];
  for (; e + 8 <= e1; e += 8) {
    int s0 = ed[e], s1 = ed[e + 1], s2 = ed[e + 2], s3 = ed[e + 3];
    int s4 = ed[e + 4], s5 = ed[e + 5], s6 = ed[e + 6], s7 = ed[e + 7];
    u16 z0 = zb[(size_t)s0 * NC + col];
    u16 z1 = zb[(size_t)s1 * NC + col];
    u16 z2 = zb[(size_t)s2 * NC + col];
    u16 z3 = zb[(size_t)s3 * NC + col];
    u16 z4 = zb[(size_t)s4 * NC + col];
    u16 z5 = zb[(size_t)s5 * NC + col];
    u16 z6 = zb[(size_t)s6 * NC + col];
    u16 z7 = zb[(size_t)s7 * NC + col];
    acc += ((bf2f(z0) + bf2f(z1)) + (bf2f(z2) + bf2f(z3))) +
           ((bf2f(z4) + bf2f(z5)) + (bf2f(z6) + bf2f(z7)));
  }
  for (; e < e1; ++e)
    acc += bf2f(zb[(size_t)ed[e] * NC + col]);
  acc = di * acc + b2[col];
  float mv = (lane < NC) ? acc : -3.0e38f;
  for (int off = 32; off > 0; off >>= 1) mv = fmaxf(mv, __shfl_xor(mv, off));
  float ex = (lane < NC) ? expf(acc - mv) : 0.f;
  float sum = ex;
  for (int off = 32; off > 0; off >>= 1) sum += __shfl_xor(sum, off);
  float res = acc - mv - logf(sum);
  if (lane < NC) out[(size_t)row * NC + lane] = res;
}

extern "C" void kernel_launch(void* const* d_in, const int* in_sizes, int n_in,
                              void* d_out, int out_size, void* d_ws, size_t ws_size,
                              hipStream_t stream) {
  const float* x  = (const float*)d_in[0];
  const int*   ei = (const int*)d_in[1];
  const float* W1 = (const float*)d_in[2];
  const float* b1 = (const float*)d_in[3];
  const float* W2 = (const float*)d_in[4];
  const float* b2 = (const float*)d_in[5];
  float* out = (float*)d_out;

  char* ws = (char*)d_ws;
  size_t off = 0;
  auto alloc = [&](size_t bytes) {
    char* p = ws + off;
    off = (off + bytes + 255) & ~(size_t)255;
    return p;
  };
  int*   gcur   = (int*)  alloc((size_t)NBUCK * 4);
  int*   rp     = (int*)  alloc((size_t)N_NODES * 4);
  int*   re     = (int*)  alloc((size_t)N_NODES * 4);
  float* dinv   = (float*)alloc((size_t)N_NODES * 4);
  u32*   binned = (u32*)  alloc((size_t)NPADE * 4);             // 25.6 MB
  int*   ed     = (int*)  alloc((size_t)NPADE * 4);             // 25.6 MB
  unsigned char* y = (unsigned char*)alloc((size_t)N_NODES * 256); // 25.6 MB fp8
  u16*   w1t    = (u16*)  alloc((size_t)256 * 256 * 2);
  u16*   w2t    = (u16*)  alloc((size_t)48 * 256 * 2);
  u16*   h1     = (u16*)  alloc((size_t)N_NODES * HID * 2);     // 51.2 MB
  u16*   zb     = (u16*)  alloc((size_t)N_NODES * NC * 2);      // 8 MB

  k_zero<<<2, 256, 0, stream>>>(gcur);
  k_bin1<<<BIN1_BLOCKS, 256, 0, stream>>>(ei, gcur, binned);
  k_bin2<<<NBUCK, 256, 0, stream>>>(binned, gcur, rp, re, dinv, ed);
  k_w1t<<<256, 256, 0, stream>>>(W1, w1t);
  k_w2t<<<48, 256, 0, stream>>>(W2, w2t);
  k_gemm1<<<dim3((N_NODES + 127) / 128, 2), 256, 0, stream>>>(x, w1t, dinv, y);
  k_spmm1<<<N_NODES / 4, 256, 0, stream>>>((const u32*)y, ed, rp, re, dinv, b1, h1);
  k_gemm2<<<(N_NODES + 127) / 128, 256, 0, stream>>>(h1, w2t, dinv, zb);
  k_spmm2<<<N_NODES / 4, 256, 0, stream>>>(zb, ed, rp, re, dinv, b2, out);
}